// Round 4
// baseline (657.989 us; speedup 1.0000x reference)
//
#include <hip/hip_runtime.h>
#include <hip/hip_bf16.h>
#include <cstdint>

#define B_ 512
#define S_ 512
#define V_ 5000
#define E_ 100
#define HD_ 64
#define T_ 25
#define START_ 1
#define STOP_ 2

typedef _Float16 half2_t __attribute__((ext_vector_type(2)));
typedef __attribute__((ext_vector_type(8))) short short8;
typedef __attribute__((ext_vector_type(4))) float f32x4;

#if __has_builtin(__builtin_amdgcn_fdot2)
__device__ inline float dot2(uint32_t a, uint32_t b, float c) {
  return __builtin_amdgcn_fdot2(__builtin_bit_cast(half2_t, a),
                                __builtin_bit_cast(half2_t, b), c, false);
}
#else
__device__ inline float dot2(uint32_t a, uint32_t b, float c) {
  half2_t ha = __builtin_bit_cast(half2_t, a);
  half2_t hb = __builtin_bit_cast(half2_t, b);
  return c + (float)ha[0] * (float)hb[0] + (float)ha[1] * (float)hb[1];
}
#endif

__device__ inline float sigm(float x) { return 1.0f / (1.0f + __expf(-x)); }
__device__ inline float tanh_(float x) { return 1.0f - 2.0f / (1.0f + __expf(2.0f * x)); }

// ---------------- K1: P[v][pk] = embed[v] . Wih[u], per dir -------------------
// pk(u) = (u>>7)*128 + (u&63)*2 + ((u>>6)&1): k_lstm wave w lane j reads
// float2 at w*128 + 2j = (x_{u0}, x_{u1}), u0 = w*128+j, u1 = u0+64.
__global__ __launch_bounds__(256) void k_proj(const float* __restrict__ embed,
                                              const float* __restrict__ Wf,
                                              const float* __restrict__ Wb,
                                              float* __restrict__ Pf,
                                              float* __restrict__ Pb) {
  __shared__ __align__(16) float embS[16 * E_];
  int v0 = blockIdx.x * 16;
  const float* Wih = blockIdx.y ? Wb : Wf;
  float* P = blockIdx.y ? Pb : Pf;
  int nv = V_ - v0; if (nv > 16) nv = 16;
  for (int idx = threadIdx.x; idx < nv * E_; idx += 256)
    embS[idx] = embed[v0 * E_ + idx];
  __syncthreads();
  int u = threadIdx.x;
  float acc[16];
#pragma unroll
  for (int i = 0; i < 16; i++) acc[i] = 0.f;
  const float4* W4 = (const float4*)(Wih + u * E_);
  const float4* e4 = (const float4*)embS;
#pragma unroll 5
  for (int q = 0; q < 25; q++) {
    float4 w = W4[q];
#pragma unroll
    for (int vi = 0; vi < 16; vi++) {
      float4 e = e4[vi * 25 + q];
      acc[vi] += w.x * e.x + w.y * e.y + w.z * e.z + w.w * e.w;
    }
  }
  int pk = (u >> 7) * 128 + (u & 63) * 2 + ((u >> 6) & 1);
  for (int vi = 0; vi < nv; vi++)
    P[(size_t)(v0 + vi) * 256 + pk] = acc[vi];
}

// ---------------- K1b: WoutPad[32][128] bf16 (rows >= 25 zero) ----------------
__global__ __launch_bounds__(256) void k_prep(const float* __restrict__ Wout,
                                              __hip_bfloat16* __restrict__ WoutP) {
  int idx = blockIdx.x * 256 + threadIdx.x;
  if (idx < 32 * 128) {
    int r = idx >> 7, c = idx & 127;
    float v = (r < T_) ? Wout[r * 128 + c] : 0.f;
    WoutP[idx] = __float2bfloat16(v);
  }
}

// ---------------- K2: BiLSTM, 1 seq = 2 waves (gate-split i,f | g,o) ----------
// Wave w lane j holds Whh rows u0 = w*128+j, u1 = w*128+64+j as f16 pairs
// (64 VGPRs — safely register-resident). Wave 1 computes tanh(g), sigm(o),
// ships 8B/lane via LDS; wave 0 owns c/h update. 2 barriers/step, 2048 waves.
__global__ __launch_bounds__(128) void k_lstm(
    const int* __restrict__ sentences,
    const float* __restrict__ Pf, const float* __restrict__ Pb,
    const float* __restrict__ Whh_f, const float* __restrict__ Whh_b,
    const float* __restrict__ bih_f, const float* __restrict__ bhh_f,
    const float* __restrict__ bih_b, const float* __restrict__ bhh_b,
    const float* __restrict__ h0, const float* __restrict__ c0,
    __hip_bfloat16* __restrict__ feat) {
  int tid = threadIdx.x;
  int j = tid & 63;                    // hidden unit
  int w = tid >> 6;                    // 0: gates i,f ; 1: gates g,o
  int seq = blockIdx.x;                // 0..1023
  int be = seq & (B_ - 1);
  int d = seq >> 9;                    // 0 fwd, 1 bwd
  const float* P   = d ? Pb : Pf;
  const float* Whh = d ? Whh_b : Whh_f;
  const float* bih = d ? bih_b : bih_f;
  const float* bhh = d ? bhh_b : bhh_f;

  __shared__ __align__(16) uint32_t hS[32];   // 64 f16 h values
  __shared__ __align__(16) float2 zS[64];     // (tanh_g, sig_o) from wave 1

  int u0 = w * 128 + j;
  int u1 = u0 + 64;
  uint32_t wA[32], wB[32];
  {
    const float4* r0 = (const float4*)(Whh + (size_t)u0 * HD_);
    const float4* r1 = (const float4*)(Whh + (size_t)u1 * HD_);
#pragma unroll
    for (int q = 0; q < 16; q++) {
      float4 a = r0[q], b = r1[q];
      union { _Float16 h[2]; uint32_t u32; } p0, p1, p2, p3;
      p0.h[0] = (_Float16)a.x; p0.h[1] = (_Float16)a.y;
      p1.h[0] = (_Float16)a.z; p1.h[1] = (_Float16)a.w;
      p2.h[0] = (_Float16)b.x; p2.h[1] = (_Float16)b.y;
      p3.h[0] = (_Float16)b.z; p3.h[1] = (_Float16)b.w;
      wA[2 * q] = p0.u32; wA[2 * q + 1] = p1.u32;
      wB[2 * q] = p2.u32; wB[2 * q + 1] = p3.u32;
    }
  }
  float bA = bih[u0] + bhh[u0];
  float bB = bih[u1] + bhh[u1];
  float c = 0.f;
  if (w == 0) {
    c = c0[(d * B_ + be) * HD_ + j];
    ((_Float16*)hS)[j] = (_Float16)h0[(d * B_ + be) * HD_ + j];
  }
  __syncthreads();

  const int* sent = sentences + (size_t)be * S_;
  int tt0 = d ? (S_ - 1) : 0;
  int stp = d ? -1 : 1;
  int tok1 = sent[tt0];
  float2 x = *(const float2*)(P + (size_t)tok1 * 256 + w * 128 + 2 * j);
  tok1 = sent[tt0 + stp];
  const uint4* hS4 = (const uint4*)hS;

  for (int t = 0; t < S_; t++) {
    int tt = tt0 + stp * t;
    float2 xn = x;
    if (t + 1 < S_)
      xn = *(const float2*)(P + (size_t)tok1 * 256 + w * 128 + 2 * j);
    int tok2 = tok1;
    if (t + 2 < S_) tok2 = sent[tt + 2 * stp];

    float a0 = 0.f, a1 = 0.f, b0 = 0.f, b1 = 0.f;
#pragma unroll
    for (int q = 0; q < 8; q++) {
      uint4 hv = hS4[q];
      int kp = 4 * q;
      a0 = dot2(wA[kp + 0], hv.x, a0); a1 = dot2(wA[kp + 1], hv.y, a1);
      a0 = dot2(wA[kp + 2], hv.z, a0); a1 = dot2(wA[kp + 3], hv.w, a1);
      b0 = dot2(wB[kp + 0], hv.x, b0); b1 = dot2(wB[kp + 1], hv.y, b1);
      b0 = dot2(wB[kp + 2], hv.z, b0); b1 = dot2(wB[kp + 3], hv.w, b1);
    }
    float zA = a0 + a1 + bA + x.x;     // w0: z_i ; w1: z_g
    float zB = b0 + b1 + bB + x.y;     // w0: z_f ; w1: z_o
    float tA = 0.f, tB = 0.f;
    if (w == 1) {
      zS[j] = make_float2(tanh_(zA), sigm(zB));
    } else {
      tA = sigm(zA);                   // i
      tB = sigm(zB);                   // f
    }
    __syncthreads();
    if (w == 0) {
      float2 go = zS[j];
      c = tB * c + tA * go.x;
      float hh = go.y * tanh_(c);
      feat[((size_t)be * S_ + tt) * 128 + d * 64 + j] = __float2bfloat16(hh);
      ((_Float16*)hS)[j] = (_Float16)hh;
    }
    __syncthreads();
    x = xn;
    tok1 = tok2;
  }
}

// ---------------- K3: logits = feat . WoutP^T + bout via MFMA -----------------
__global__ __launch_bounds__(256) void k_logits(const __hip_bfloat16* __restrict__ feat,
                                                const __hip_bfloat16* __restrict__ WoutP,
                                                const float* __restrict__ bout,
                                                float* __restrict__ logits) {
  int w = threadIdx.x >> 6, l = threadIdx.x & 63;
  size_t r0 = ((size_t)blockIdx.x * 4 + w) * 16;
  int mrow = l & 15, kg = l >> 4;
  short8 bfr[2][4];
#pragma unroll
  for (int nt = 0; nt < 2; nt++) {
    int n = nt * 16 + mrow;
#pragma unroll
    for (int kb = 0; kb < 4; kb++)
      bfr[nt][kb] = *(const short8*)(WoutP + n * 128 + kb * 32 + kg * 8);
  }
  f32x4 acc[2];
#pragma unroll
  for (int nt = 0; nt < 2; nt++) {
    int col = nt * 16 + mrow;
    float bb = (col < T_) ? bout[col] : 0.f;
    acc[nt] = (f32x4){bb, bb, bb, bb};
  }
#pragma unroll
  for (int kb = 0; kb < 4; kb++) {
    short8 a = *(const short8*)(feat + (r0 + mrow) * 128 + kb * 32 + kg * 8);
    acc[0] = __builtin_amdgcn_mfma_f32_16x16x32_bf16(a, bfr[0][kb], acc[0], 0, 0, 0);
    acc[1] = __builtin_amdgcn_mfma_f32_16x16x32_bf16(a, bfr[1][kb], acc[1], 0, 0, 0);
  }
#pragma unroll
  for (int nt = 0; nt < 2; nt++) {
    int col = nt * 16 + mrow;
    if (col < T_) {
#pragma unroll
      for (int q = 0; q < 4; q++) {
        int row = kg * 4 + q;
        logits[(r0 + row) * T_ + col] = acc[nt][q];
      }
    }
  }
}

// ---------------- K4: CRF forward, 1 wave = 1 batch elem ---------------------
__global__ __launch_bounds__(64) void k_crf(const float* __restrict__ logits,
                                            const float* __restrict__ trans,
                                            float* __restrict__ totals) {
  int j = threadIdx.x;
  int b = blockIdx.x;
  bool act = j < T_;
  __shared__ __align__(16) float qS[32];
  float Ecol[T_];
#pragma unroll
  for (int i = 0; i < T_; i++)
    Ecol[i] = act ? __expf(trans[i * T_ + j]) : 0.f;
  if (j >= T_ && j < 32) qS[j] = 0.f;
  float tstop = act ? trans[j * T_ + STOP_] : 0.f;
  float prev = act ? 0.f : -INFINITY;
  const float* lg = logits + (size_t)b * S_ * T_;
  float ltn = act ? lg[j] : 0.f;
  asm volatile("s_waitcnt lgkmcnt(0)" ::: "memory");
  for (int t = 0; t < S_; t++) {
    float lt = ltn;
    if (t + 1 < S_) ltn = act ? lg[(size_t)(t + 1) * T_ + j] : 0.f;
    float m = __builtin_bit_cast(float,
        __builtin_amdgcn_readfirstlane(__builtin_bit_cast(int, prev)));
    float q = __expf(prev - m);
    if (act) qS[j] = q;
    asm volatile("s_waitcnt lgkmcnt(0)" ::: "memory");
    const float4* q4 = (const float4*)qS;
    float4 qv0 = q4[0], qv1 = q4[1], qv2 = q4[2], qv3 = q4[3];
    float4 qv4 = q4[4], qv5 = q4[5], qv6 = q4[6];
    float s0, s1, s2, s3;
    s0 = qv0.x * Ecol[0];  s1 = qv0.y * Ecol[1];
    s2 = qv0.z * Ecol[2];  s3 = qv0.w * Ecol[3];
    s0 += qv1.x * Ecol[4];  s1 += qv1.y * Ecol[5];
    s2 += qv1.z * Ecol[6];  s3 += qv1.w * Ecol[7];
    s0 += qv2.x * Ecol[8];  s1 += qv2.y * Ecol[9];
    s2 += qv2.z * Ecol[10]; s3 += qv2.w * Ecol[11];
    s0 += qv3.x * Ecol[12]; s1 += qv3.y * Ecol[13];
    s2 += qv3.z * Ecol[14]; s3 += qv3.w * Ecol[15];
    s0 += qv4.x * Ecol[16]; s1 += qv4.y * Ecol[17];
    s2 += qv4.z * Ecol[18]; s3 += qv4.w * Ecol[19];
    s0 += qv5.x * Ecol[20]; s1 += qv5.y * Ecol[21];
    s2 += qv5.z * Ecol[22]; s3 += qv5.w * Ecol[23];
    s0 += qv6.x * Ecol[24];
    float s = (s0 + s1) + (s2 + s3);
    prev = lt + m + __logf(s);
    if (!act) prev = -INFINITY;
  }
  float v = prev + tstop;
  float m = v;
#pragma unroll
  for (int off = 32; off > 0; off >>= 1)
    m = fmaxf(m, __shfl_xor(m, off, 64));
  float e = __expf(v - m);
#pragma unroll
  for (int off = 32; off > 0; off >>= 1)
    e += __shfl_xor(e, off, 64);
  if (j == 0) totals[b] = m + __logf(e);
}

// ---------------- K5: gold path score per b ----------------------------------
__global__ __launch_bounds__(256) void k_real(const float* __restrict__ logits,
                                              const int* __restrict__ tags,
                                              const float* __restrict__ trans,
                                              float* __restrict__ reals) {
  __shared__ float red[256];
  int b = blockIdx.x;
  float acc = 0.f;
  for (int s = threadIdx.x; s < S_; s += 256) {
    int tg = tags[(size_t)b * S_ + s];
    int pv = (s == 0) ? START_ : tags[(size_t)b * S_ + s - 1];
    acc += logits[((size_t)b * S_ + s) * T_ + tg] + trans[pv * T_ + tg];
  }
  red[threadIdx.x] = acc;
  __syncthreads();
  for (int off = 128; off > 0; off >>= 1) {
    if (threadIdx.x < off) red[threadIdx.x] += red[threadIdx.x + off];
    __syncthreads();
  }
  if (threadIdx.x == 0)
    reals[b] = red[0] + trans[tags[(size_t)b * S_ + S_ - 1] * T_ + STOP_];
}

// ---------------- K6: out = sum_b totals - reals -----------------------------
__global__ __launch_bounds__(256) void k_final(const float* __restrict__ totals,
                                               const float* __restrict__ reals,
                                               float* __restrict__ out) {
  __shared__ float red[256];
  float acc = 0.f;
  for (int b = threadIdx.x; b < B_; b += 256) acc += totals[b] - reals[b];
  red[threadIdx.x] = acc;
  __syncthreads();
  for (int off = 128; off > 0; off >>= 1) {
    if (threadIdx.x < off) red[threadIdx.x] += red[threadIdx.x + off];
    __syncthreads();
  }
  if (threadIdx.x == 0) out[0] = red[0];
}

// ws: Pf 5,120,000 | Pb 5,120,000 | feat(bf16) 67,108,864 | logits 26,214,400
//   | WoutP 8,192 | totals 2,048 | reals 2,048
extern "C" void kernel_launch(void* const* d_in, const int* in_sizes, int n_in,
                              void* d_out, int out_size, void* d_ws, size_t ws_size,
                              hipStream_t stream) {
  const int*   sentences = (const int*)d_in[0];
  const int*   tags  = (const int*)d_in[1];
  const float* embed = (const float*)d_in[2];
  const float* Wih_f = (const float*)d_in[3];
  const float* Whh_f = (const float*)d_in[4];
  const float* bih_f = (const float*)d_in[5];
  const float* bhh_f = (const float*)d_in[6];
  const float* Wih_b = (const float*)d_in[7];
  const float* Whh_b = (const float*)d_in[8];
  const float* bih_b = (const float*)d_in[9];
  const float* bhh_b = (const float*)d_in[10];
  const float* h0    = (const float*)d_in[11];
  const float* c0    = (const float*)d_in[12];
  const float* Wout  = (const float*)d_in[13];
  const float* bout  = (const float*)d_in[14];
  const float* trans = (const float*)d_in[15];

  char* ws = (char*)d_ws;
  float* Pf = (float*)(ws);
  float* Pb = (float*)(ws + 5120000);
  __hip_bfloat16* feat = (__hip_bfloat16*)(ws + 10240000);
  float* logits = (float*)(ws + 10240000 + 67108864);
  __hip_bfloat16* WoutP = (__hip_bfloat16*)(ws + 10240000 + 67108864 + 26214400);
  float* totals = (float*)(ws + 10240000 + 67108864 + 26214400 + 8192);
  float* reals  = totals + B_;
  float* out    = (float*)d_out;

  k_proj<<<dim3(313, 2), 256, 0, stream>>>(embed, Wih_f, Wih_b, Pf, Pb);
  k_prep<<<16, 256, 0, stream>>>(Wout, WoutP);
  k_lstm<<<1024, 128, 0, stream>>>(sentences, Pf, Pb, Whh_f, Whh_b,
                                   bih_f, bhh_f, bih_b, bhh_b, h0, c0, feat);
  k_logits<<<4096, 256, 0, stream>>>(feat, WoutP, bout, logits);
  k_crf<<<512, 64, 0, stream>>>(logits, trans, totals);
  k_real<<<512, 256, 0, stream>>>(logits, tags, trans, reals);
  k_final<<<1, 256, 0, stream>>>(totals, reals, out);
}

// Round 5
// 557.335 us; speedup vs baseline: 1.1806x; 1.1806x over previous
//
#include <hip/hip_runtime.h>
#include <hip/hip_bf16.h>
#include <cstdint>

#define B_ 512
#define S_ 512
#define V_ 5000
#define E_ 100
#define HD_ 64
#define T_ 25
#define START_ 1
#define STOP_ 2

typedef _Float16 half2_t __attribute__((ext_vector_type(2)));
typedef __attribute__((ext_vector_type(8))) short short8;
typedef __attribute__((ext_vector_type(4))) float f32x4;

#if __has_builtin(__builtin_amdgcn_fdot2)
__device__ inline float dot2(uint32_t a, uint32_t b, float c) {
  return __builtin_amdgcn_fdot2(__builtin_bit_cast(half2_t, a),
                                __builtin_bit_cast(half2_t, b), c, false);
}
#else
__device__ inline float dot2(uint32_t a, uint32_t b, float c) {
  half2_t ha = __builtin_bit_cast(half2_t, a);
  half2_t hb = __builtin_bit_cast(half2_t, b);
  return c + (float)ha[0] * (float)hb[0] + (float)ha[1] * (float)hb[1];
}
#endif

__device__ inline float sigm(float x) { return 1.0f / (1.0f + __expf(-x)); }
__device__ inline float tanh_(float x) { return 1.0f - 2.0f / (1.0f + __expf(2.0f * x)); }

// ---------------- K1: P[v][j*4+g] = embed[v] . Wih[g*64+j], per dir ----------
// k_lstm lane j loads float4 = (x_i, x_f, x_g, x_o) for hidden j, coalesced.
__global__ __launch_bounds__(256) void k_proj(const float* __restrict__ embed,
                                              const float* __restrict__ Wf,
                                              const float* __restrict__ Wb,
                                              float* __restrict__ Pf,
                                              float* __restrict__ Pb) {
  __shared__ __align__(16) float embS[16 * E_];
  int v0 = blockIdx.x * 16;
  const float* Wih = blockIdx.y ? Wb : Wf;
  float* P = blockIdx.y ? Pb : Pf;
  int nv = V_ - v0; if (nv > 16) nv = 16;
  for (int idx = threadIdx.x; idx < nv * E_; idx += 256)
    embS[idx] = embed[v0 * E_ + idx];
  __syncthreads();
  int u = threadIdx.x;
  float acc[16];
#pragma unroll
  for (int i = 0; i < 16; i++) acc[i] = 0.f;
  const float4* W4 = (const float4*)(Wih + u * E_);
  const float4* e4 = (const float4*)embS;
#pragma unroll 5
  for (int q = 0; q < 25; q++) {
    float4 w = W4[q];
#pragma unroll
    for (int vi = 0; vi < 16; vi++) {
      float4 e = e4[vi * 25 + q];
      acc[vi] += w.x * e.x + w.y * e.y + w.z * e.z + w.w * e.w;
    }
  }
  int pk = (u & 63) * 4 + (u >> 6);   // hidden j -> float4 slot, gate -> comp
  for (int vi = 0; vi < nv; vi++)
    P[(size_t)(v0 + vi) * 256 + pk] = acc[vi];
}

// ---------------- K1b: WoutPad[32][128] bf16 (rows >= 25 zero) ----------------
__global__ __launch_bounds__(256) void k_prep(const float* __restrict__ Wout,
                                              __hip_bfloat16* __restrict__ WoutP) {
  int idx = blockIdx.x * 256 + threadIdx.x;
  if (idx < 32 * 128) {
    int r = idx >> 7, c = idx & 127;
    float v = (r < T_) ? Wout[r * 128 + c] : 0.f;
    WoutP[idx] = __float2bfloat16(v);
  }
}

// ---------------- K2: BiLSTM: 1 wave = 1 seq, no barriers, weights in VGPRs --
// amdgpu_waves_per_eu(1,1): pin 1 wave/SIMD -> full 256 arch-VGPR budget so
// wp[4][32] (128 regs) stays in arch VGPRs (r3 showed AGPR demotion at the
// default budget: VGPR_Count=96 < architectural need, ~128 v_accvgpr_read on
// the critical path). 16 accumulator chains shorten dot dep-depth to 8.
__global__ __attribute__((amdgpu_waves_per_eu(1, 1))) __launch_bounds__(64)
void k_lstm(
    const int* __restrict__ sentences,
    const float* __restrict__ Pf, const float* __restrict__ Pb,
    const float* __restrict__ Whh_f, const float* __restrict__ Whh_b,
    const float* __restrict__ bih_f, const float* __restrict__ bhh_f,
    const float* __restrict__ bih_b, const float* __restrict__ bhh_b,
    const float* __restrict__ h0, const float* __restrict__ c0,
    __hip_bfloat16* __restrict__ feat) {
  int j = threadIdx.x;                 // 0..63 = hidden unit
  int seq = blockIdx.x;                // 0..1023
  int be = seq & (B_ - 1);
  int d = seq >> 9;                    // 0 fwd, 1 bwd
  const float* P   = d ? Pb : Pf;
  const float* Whh = d ? Whh_b : Whh_f;
  const float* bih = d ? bih_b : bih_f;
  const float* bhh = d ? bhh_b : bhh_f;

  __shared__ __align__(16) uint32_t hS[32];   // 64 f16 h values

  // Whh rows u = g*64 + j as f16 pairs: wp[g][kp] = (W[u][2kp], W[u][2kp+1])
  uint32_t wp[4][32];
  float bg[4];
#pragma unroll
  for (int g = 0; g < 4; g++) {
    int u = g * 64 + j;
    const float4* rp = (const float4*)(Whh + (size_t)u * HD_);
#pragma unroll
    for (int q = 0; q < 16; q++) {
      float4 a = rp[q];
      union { _Float16 h[2]; uint32_t u32; } p0, p1;
      p0.h[0] = (_Float16)a.x; p0.h[1] = (_Float16)a.y;
      p1.h[0] = (_Float16)a.z; p1.h[1] = (_Float16)a.w;
      wp[g][2 * q] = p0.u32; wp[g][2 * q + 1] = p1.u32;
    }
    bg[g] = bih[u] + bhh[u];
  }
  float c = c0[(d * B_ + be) * HD_ + j];
  ((_Float16*)hS)[j] = (_Float16)h0[(d * B_ + be) * HD_ + j];
  asm volatile("s_waitcnt lgkmcnt(0)" ::: "memory");

  const int* sent = sentences + (size_t)be * S_;
  int tt0 = d ? (S_ - 1) : 0;
  int stp = d ? -1 : 1;
  int tok1 = sent[tt0];
  const float4* P4 = (const float4*)P;
  float4 x = P4[(size_t)tok1 * 64 + j];
  tok1 = sent[tt0 + stp];
  const uint4* hS4 = (const uint4*)hS;

  for (int t = 0; t < S_; t++) {
    int tt = tt0 + stp * t;
    float4 xn = x;
    if (t + 1 < S_) xn = P4[(size_t)tok1 * 64 + j];
    int tok2 = tok1;
    if (t + 2 < S_) tok2 = sent[tt + 2 * stp];

    float ac[4][4];
#pragma unroll
    for (int g = 0; g < 4; g++)
#pragma unroll
      for (int i = 0; i < 4; i++) ac[g][i] = 0.f;
#pragma unroll
    for (int q = 0; q < 8; q++) {
      uint4 hv = hS4[q];
      int kp = 4 * q;
#pragma unroll
      for (int g = 0; g < 4; g++) {
        ac[g][0] = dot2(wp[g][kp + 0], hv.x, ac[g][0]);
        ac[g][1] = dot2(wp[g][kp + 1], hv.y, ac[g][1]);
        ac[g][2] = dot2(wp[g][kp + 2], hv.z, ac[g][2]);
        ac[g][3] = dot2(wp[g][kp + 3], hv.w, ac[g][3]);
      }
    }
    float zi = (ac[0][0] + ac[0][1]) + (ac[0][2] + ac[0][3]) + bg[0] + x.x;
    float zf = (ac[1][0] + ac[1][1]) + (ac[1][2] + ac[1][3]) + bg[1] + x.y;
    float zg = (ac[2][0] + ac[2][1]) + (ac[2][2] + ac[2][3]) + bg[2] + x.z;
    float zo = (ac[3][0] + ac[3][1]) + (ac[3][2] + ac[3][3]) + bg[3] + x.w;
    c = sigm(zf) * c + sigm(zi) * tanh_(zg);
    float hh = sigm(zo) * tanh_(c);
    feat[((size_t)be * S_ + tt) * 128 + d * 64 + j] = __float2bfloat16(hh);
    ((_Float16*)hS)[j] = (_Float16)hh;
    asm volatile("s_waitcnt lgkmcnt(0)" ::: "memory");
    x = xn;
    tok1 = tok2;
  }
}

// ---------------- K3: logits = feat . WoutP^T + bout via MFMA -----------------
__global__ __launch_bounds__(256) void k_logits(const __hip_bfloat16* __restrict__ feat,
                                                const __hip_bfloat16* __restrict__ WoutP,
                                                const float* __restrict__ bout,
                                                float* __restrict__ logits) {
  int w = threadIdx.x >> 6, l = threadIdx.x & 63;
  size_t r0 = ((size_t)blockIdx.x * 4 + w) * 16;
  int mrow = l & 15, kg = l >> 4;
  short8 bfr[2][4];
#pragma unroll
  for (int nt = 0; nt < 2; nt++) {
    int n = nt * 16 + mrow;
#pragma unroll
    for (int kb = 0; kb < 4; kb++)
      bfr[nt][kb] = *(const short8*)(WoutP + n * 128 + kb * 32 + kg * 8);
  }
  f32x4 acc[2];
#pragma unroll
  for (int nt = 0; nt < 2; nt++) {
    int col = nt * 16 + mrow;
    float bb = (col < T_) ? bout[col] : 0.f;
    acc[nt] = (f32x4){bb, bb, bb, bb};
  }
#pragma unroll
  for (int kb = 0; kb < 4; kb++) {
    short8 a = *(const short8*)(feat + (r0 + mrow) * 128 + kb * 32 + kg * 8);
    acc[0] = __builtin_amdgcn_mfma_f32_16x16x32_bf16(a, bfr[0][kb], acc[0], 0, 0, 0);
    acc[1] = __builtin_amdgcn_mfma_f32_16x16x32_bf16(a, bfr[1][kb], acc[1], 0, 0, 0);
  }
#pragma unroll
  for (int nt = 0; nt < 2; nt++) {
    int col = nt * 16 + mrow;
    if (col < T_) {
#pragma unroll
      for (int q = 0; q < 4; q++) {
        int row = kg * 4 + q;
        logits[(r0 + row) * T_ + col] = acc[nt][q];
      }
    }
  }
}

// ---------------- K4: CRF forward, 1 wave = 1 batch elem ---------------------
__global__ __launch_bounds__(64) void k_crf(const float* __restrict__ logits,
                                            const float* __restrict__ trans,
                                            float* __restrict__ totals) {
  int j = threadIdx.x;
  int b = blockIdx.x;
  bool act = j < T_;
  __shared__ __align__(16) float qS[32];
  float Ecol[T_];
#pragma unroll
  for (int i = 0; i < T_; i++)
    Ecol[i] = act ? __expf(trans[i * T_ + j]) : 0.f;
  if (j >= T_ && j < 32) qS[j] = 0.f;
  float tstop = act ? trans[j * T_ + STOP_] : 0.f;
  float prev = act ? 0.f : -INFINITY;
  const float* lg = logits + (size_t)b * S_ * T_;
  float ltn = act ? lg[j] : 0.f;
  asm volatile("s_waitcnt lgkmcnt(0)" ::: "memory");
  for (int t = 0; t < S_; t++) {
    float lt = ltn;
    if (t + 1 < S_) ltn = act ? lg[(size_t)(t + 1) * T_ + j] : 0.f;
    float m = __builtin_bit_cast(float,
        __builtin_amdgcn_readfirstlane(__builtin_bit_cast(int, prev)));
    float q = __expf(prev - m);
    if (act) qS[j] = q;
    asm volatile("s_waitcnt lgkmcnt(0)" ::: "memory");
    const float4* q4 = (const float4*)qS;
    float4 qv0 = q4[0], qv1 = q4[1], qv2 = q4[2], qv3 = q4[3];
    float4 qv4 = q4[4], qv5 = q4[5], qv6 = q4[6];
    float s0, s1, s2, s3;
    s0 = qv0.x * Ecol[0];  s1 = qv0.y * Ecol[1];
    s2 = qv0.z * Ecol[2];  s3 = qv0.w * Ecol[3];
    s0 += qv1.x * Ecol[4];  s1 += qv1.y * Ecol[5];
    s2 += qv1.z * Ecol[6];  s3 += qv1.w * Ecol[7];
    s0 += qv2.x * Ecol[8];  s1 += qv2.y * Ecol[9];
    s2 += qv2.z * Ecol[10]; s3 += qv2.w * Ecol[11];
    s0 += qv3.x * Ecol[12]; s1 += qv3.y * Ecol[13];
    s2 += qv3.z * Ecol[14]; s3 += qv3.w * Ecol[15];
    s0 += qv4.x * Ecol[16]; s1 += qv4.y * Ecol[17];
    s2 += qv4.z * Ecol[18]; s3 += qv4.w * Ecol[19];
    s0 += qv5.x * Ecol[20]; s1 += qv5.y * Ecol[21];
    s2 += qv5.z * Ecol[22]; s3 += qv5.w * Ecol[23];
    s0 += qv6.x * Ecol[24];
    float s = (s0 + s1) + (s2 + s3);
    prev = lt + m + __logf(s);
    if (!act) prev = -INFINITY;
  }
  float v = prev + tstop;
  float m = v;
#pragma unroll
  for (int off = 32; off > 0; off >>= 1)
    m = fmaxf(m, __shfl_xor(m, off, 64));
  float e = __expf(v - m);
#pragma unroll
  for (int off = 32; off > 0; off >>= 1)
    e += __shfl_xor(e, off, 64);
  if (j == 0) totals[b] = m + __logf(e);
}

// ---------------- K5: gold path score per b ----------------------------------
__global__ __launch_bounds__(256) void k_real(const float* __restrict__ logits,
                                              const int* __restrict__ tags,
                                              const float* __restrict__ trans,
                                              float* __restrict__ reals) {
  __shared__ float red[256];
  int b = blockIdx.x;
  float acc = 0.f;
  for (int s = threadIdx.x; s < S_; s += 256) {
    int tg = tags[(size_t)b * S_ + s];
    int pv = (s == 0) ? START_ : tags[(size_t)b * S_ + s - 1];
    acc += logits[((size_t)b * S_ + s) * T_ + tg] + trans[pv * T_ + tg];
  }
  red[threadIdx.x] = acc;
  __syncthreads();
  for (int off = 128; off > 0; off >>= 1) {
    if (threadIdx.x < off) red[threadIdx.x] += red[threadIdx.x + off];
    __syncthreads();
  }
  if (threadIdx.x == 0)
    reals[b] = red[0] + trans[tags[(size_t)b * S_ + S_ - 1] * T_ + STOP_];
}

// ---------------- K6: out = sum_b totals - reals -----------------------------
__global__ __launch_bounds__(256) void k_final(const float* __restrict__ totals,
                                               const float* __restrict__ reals,
                                               float* __restrict__ out) {
  __shared__ float red[256];
  float acc = 0.f;
  for (int b = threadIdx.x; b < B_; b += 256) acc += totals[b] - reals[b];
  red[threadIdx.x] = acc;
  __syncthreads();
  for (int off = 128; off > 0; off >>= 1) {
    if (threadIdx.x < off) red[threadIdx.x] += red[threadIdx.x + off];
    __syncthreads();
  }
  if (threadIdx.x == 0) out[0] = red[0];
}

// ws: Pf 5,120,000 | Pb 5,120,000 | feat(bf16) 67,108,864 | logits 26,214,400
//   | WoutP 8,192 | totals 2,048 | reals 2,048
extern "C" void kernel_launch(void* const* d_in, const int* in_sizes, int n_in,
                              void* d_out, int out_size, void* d_ws, size_t ws_size,
                              hipStream_t stream) {
  const int*   sentences = (const int*)d_in[0];
  const int*   tags  = (const int*)d_in[1];
  const float* embed = (const float*)d_in[2];
  const float* Wih_f = (const float*)d_in[3];
  const float* Whh_f = (const float*)d_in[4];
  const float* bih_f = (const float*)d_in[5];
  const float* bhh_f = (const float*)d_in[6];
  const float* Wih_b = (const float*)d_in[7];
  const float* Whh_b = (const float*)d_in[8];
  const float* bih_b = (const float*)d_in[9];
  const float* bhh_b = (const float*)d_in[10];
  const float* h0    = (const float*)d_in[11];
  const float* c0    = (const float*)d_in[12];
  const float* Wout  = (const float*)d_in[13];
  const float* bout  = (const float*)d_in[14];
  const float* trans = (const float*)d_in[15];

  char* ws = (char*)d_ws;
  float* Pf = (float*)(ws);
  float* Pb = (float*)(ws + 5120000);
  __hip_bfloat16* feat = (__hip_bfloat16*)(ws + 10240000);
  float* logits = (float*)(ws + 10240000 + 67108864);
  __hip_bfloat16* WoutP = (__hip_bfloat16*)(ws + 10240000 + 67108864 + 26214400);
  float* totals = (float*)(ws + 10240000 + 67108864 + 26214400 + 8192);
  float* reals  = totals + B_;
  float* out    = (float*)d_out;

  k_proj<<<dim3(313, 2), 256, 0, stream>>>(embed, Wih_f, Wih_b, Pf, Pb);
  k_prep<<<16, 256, 0, stream>>>(Wout, WoutP);
  k_lstm<<<1024, 64, 0, stream>>>(sentences, Pf, Pb, Whh_f, Whh_b,
                                  bih_f, bhh_f, bih_b, bhh_b, h0, c0, feat);
  k_logits<<<4096, 256, 0, stream>>>(feat, WoutP, bout, logits);
  k_crf<<<512, 64, 0, stream>>>(logits, trans, totals);
  k_real<<<512, 256, 0, stream>>>(logits, tags, trans, reals);
  k_final<<<1, 256, 0, stream>>>(totals, reals, out);
}